// Round 7
// baseline (345.982 us; speedup 1.0000x reference)
//
#include <hip/hip_runtime.h>
#include <hip/hip_fp16.h>
#include <math.h>

#define N_NODES 50000
#define N_EDGES 800000
#define FEAT 128
#define EPS_W 1e-12f

// Q24 fixed-point packing: low 40 bits = sum of w*2^24, high 24 bits = count.
#define WSCALE 16777216.0f
#define MASK40 ((1ull << 40) - 1)

#define CHUNKS 16
#define CHUNK_E 50000      // N_EDGES / CHUNKS
#define RANGES 8
#define RANGE_N 6250       // N_NODES / RANGES
#define HIST_BLOCKS (2 * CHUNKS * RANGES)   // 256 (src + dst flavors)
#define GEMM_BLOCKS 3125   // 50000 / 16
#define EDGE_BLOCKS 3125   // 800000 / 256

typedef unsigned long long u64;

// ---------- helpers ----------
__device__ __forceinline__ float selu_f(float x) {
  const float scale = 1.0507009873554805f;
  const float alpha = 1.6732632423543772f;
  return x > 0.f ? scale * x : scale * alpha * expm1f(x);
}

__device__ __forceinline__ float2 h2f2(unsigned int u) {
  __half2 h = *reinterpret_cast<__half2*>(&u);
  return __half22float2(h);
}

// ---------- GEMM body: 16 rows of A (n x 128) @ W (128 x 128) -> fp16 out ------
__device__ __forceinline__ void gemm16_half_body(
    const float* __restrict__ A, const float* __restrict__ W,
    __half* __restrict__ out, int row0, int n, float* aL /*16*128 LDS*/) {
  for (int i = threadIdx.x; i < 16 * 128; i += 256) {
    int r = row0 + (i >> 7);
    aL[i] = (r < n) ? A[row0 * 128 + i] : 0.f;
  }
  __syncthreads();
  int col = threadIdx.x & 63;
  int rg = threadIdx.x >> 6;  // 0..3
  float acc[4][2] = {};
  const float4* a4 = (const float4*)&aL[rg * 4 * 128];
#pragma unroll 8
  for (int k4 = 0; k4 < 32; ++k4) {
    float w0 = W[(4 * k4 + 0) * 128 + col];
    float w1 = W[(4 * k4 + 1) * 128 + col];
    float w2 = W[(4 * k4 + 2) * 128 + col];
    float w3 = W[(4 * k4 + 3) * 128 + col];
    float e0 = W[(4 * k4 + 0) * 128 + col + 64];
    float e1 = W[(4 * k4 + 1) * 128 + col + 64];
    float e2 = W[(4 * k4 + 2) * 128 + col + 64];
    float e3 = W[(4 * k4 + 3) * 128 + col + 64];
#pragma unroll
    for (int r = 0; r < 4; ++r) {
      float4 a = a4[r * 32 + k4];
      acc[r][0] += a.x * w0 + a.y * w1 + a.z * w2 + a.w * w3;
      acc[r][1] += a.x * e0 + a.y * e1 + a.z * e2 + a.w * e3;
    }
  }
#pragma unroll
  for (int r = 0; r < 4; ++r) {
    int row = row0 + rg * 4 + r;
    if (row < n) {
      out[(size_t)row * 128 + col]      = __float2half_rn(acc[r][0]);
      out[(size_t)row * 128 + col + 64] = __float2half_rn(acc[r][1]);
    }
  }
}

// ---------- 1. FUSED: LDS-histogram degrees (NO global atomics) || x@W1 GEMM ---
// Block flavors: [0,128) src-hist, [128,256) dst-hist (+rank capture),
// [256, 256+3125) GEMM. 50KB union LDS -> 3 blocks/CU, 12 waves.
// hist block (c, r): private 6250-entry u64 histogram of chunk c's endpoints in
// node range r; writes the per-chunk partial slice (plain coalesced stores).
__global__ __launch_bounds__(256) void fused_hist_gemm(
    const int* __restrict__ src, const int* __restrict__ dst,
    const float* __restrict__ ew,
    u64* __restrict__ src_part, u64* __restrict__ dst_part,
    unsigned short* __restrict__ r_local,
    const float* __restrict__ x, const float* __restrict__ W1,
    __half* __restrict__ bufG) {
  __shared__ __align__(16) unsigned char smem[RANGE_N * 8];  // 50,000 B union
  int b = blockIdx.x;
  if (b < HIST_BLOCKS) {
    u64* hist = (u64*)smem;
    int is_dst = (b >= CHUNKS * RANGES);
    int hid = is_dst ? (b - CHUNKS * RANGES) : b;
    int c = hid >> 3;             // chunk 0..15
    int lo = (hid & 7) * RANGE_N; // node-range base
    for (int i = threadIdx.x; i < RANGE_N; i += 256) hist[i] = 0;
    __syncthreads();
    int ebase = c * CHUNK_E;
    const int* __restrict__ idx = is_dst ? dst : src;
    for (int i = threadIdx.x; i < CHUNK_E; i += 256) {
      int e = ebase + i;
      int v = idx[e];
      unsigned int vl = (unsigned int)(v - lo);
      if (vl < RANGE_N) {
        float w = ew[e];
        u64 p = (1ull << 40) | (u64)llrintf(w * WSCALE);
        u64 old = atomicAdd(&hist[vl], p);      // ds_add_rtn_u64, LDS-speed
        if (is_dst) r_local[e] = (unsigned short)(old >> 40);
      }
    }
    __syncthreads();
    u64* part = (is_dst ? dst_part : src_part) + (size_t)c * N_NODES + lo;
    for (int i = threadIdx.x; i < RANGE_N; i += 256) part[i] = hist[i];
  } else {
    float* aL = (float*)smem;
    int row0 = (b - HIST_BLOCKS) * 16;
    gemm16_half_body(x, W1, bufG, row0, N_NODES, aL);
  }
}

// ---------- 2. reduce partials -> inv norms, cnt_in, per-chunk base table ------
__global__ __launch_bounds__(256) void reduce_base(
    const u64* __restrict__ src_part, const u64* __restrict__ dst_part,
    float* __restrict__ inv_out, float* __restrict__ inv_in,
    int* __restrict__ cnt_in, unsigned short* __restrict__ base_tbl) {
  int v = blockIdx.x * 256 + threadIdx.x;
  if (v >= N_NODES) return;
  u64 sw = 0; unsigned int sc = 0;
#pragma unroll
  for (int c = 0; c < CHUNKS; ++c) {
    u64 p = src_part[(size_t)c * N_NODES + v];
    sw += p & MASK40; sc += (unsigned int)(p >> 40);
  }
  u64 dw = 0; unsigned int run = 0;
#pragma unroll
  for (int c = 0; c < CHUNKS; ++c) {
    u64 p = dst_part[(size_t)c * N_NODES + v];
    base_tbl[(size_t)c * N_NODES + v] = (unsigned short)run;  // exclusive base
    dw += p & MASK40; run += (unsigned int)(p >> 40);
  }
  float wo = (float)sw * (1.0f / WSCALE);
  float wi = (float)dw * (1.0f / WSCALE);
  inv_out[v] = (1.0f / sqrtf(fmaxf(wo, EPS_W))) * (1.0f / sqrtf(fmaxf((float)sc, 1.0f)));
  inv_in[v]  = (1.0f / sqrtf(fmaxf(wi, EPS_W))) * (1.0f / sqrtf(fmaxf((float)run, 1.0f)));
  cnt_in[v] = (int)run;
}

// ---------- 3. exclusive scan of cnt_in -> rowptr ----------
__global__ __launch_bounds__(256) void scan_partial(
    const int* __restrict__ cnt, int* __restrict__ partials, int n) {
  __shared__ int sdata[256];
  int base = blockIdx.x * 1024;
  int sum = 0;
  for (int j = 0; j < 4; ++j) {
    int i = base + j * 256 + threadIdx.x;
    sum += (i < n) ? cnt[i] : 0;
  }
  sdata[threadIdx.x] = sum;
  __syncthreads();
  for (int s = 128; s > 0; s >>= 1) {
    if (threadIdx.x < (unsigned)s) sdata[threadIdx.x] += sdata[threadIdx.x + s];
    __syncthreads();
  }
  if (threadIdx.x == 0) partials[blockIdx.x] = sdata[0];
}

__global__ void scan_small(int* __restrict__ partials, int nb) {
  int lane = threadIdx.x;  // launched with 64 threads, nb <= 64
  int v = (lane < nb) ? partials[lane] : 0;
  int incl = v;
#pragma unroll
  for (int off = 1; off < 64; off <<= 1) {
    int tv = __shfl_up(incl, off);
    if (lane >= off) incl += tv;
  }
  if (lane < nb) partials[lane] = incl - v;  // exclusive
}

__global__ __launch_bounds__(256) void scan_write(
    const int* __restrict__ cnt, const int* __restrict__ partials,
    int* __restrict__ rowptr, int n) {
  __shared__ int sh[256];
  int t = threadIdx.x;
  int base = blockIdx.x * 1024;
  int c[4], local[4], s = 0;
#pragma unroll
  for (int j = 0; j < 4; ++j) {
    int i = base + t * 4 + j;
    c[j] = (i < n) ? cnt[i] : 0;
    s += c[j];
    local[j] = s;  // inclusive within thread
  }
  sh[t] = s;
  __syncthreads();
  for (int off = 1; off < 256; off <<= 1) {
    int v = (t >= off) ? sh[t - off] : 0;
    __syncthreads();
    sh[t] += v;
    __syncthreads();
  }
  int thread_excl = sh[t] - s;
  int pbase = partials[blockIdx.x];
#pragma unroll
  for (int j = 0; j < 4; ++j) {
    int i = base + t * 4 + j;
    if (i < n) {
      int excl = pbase + thread_excl + local[j] - c[j];
      rowptr[i] = excl;
      if (i == n - 1) rowptr[n] = excl + c[j];
    }
  }
}

// ---------- 4. ATOMIC-FREE fill: pos = rowptr[d] + base[chunk][d] + r_local ----
__global__ __launch_bounds__(256) void fill_kernel(
    const int* __restrict__ src, const int* __restrict__ dst,
    const float* __restrict__ ew,
    const float* __restrict__ inv_out, const float* __restrict__ inv_in,
    const int* __restrict__ rowptr, const unsigned short* __restrict__ base_tbl,
    const unsigned short* __restrict__ r_local, int2* __restrict__ edges) {
  int e = blockIdx.x * 256 + threadIdx.x;
  if (e >= N_EDGES) return;
  int s = src[e], d = dst[e];
  float c = ew[e] * inv_out[s] * inv_in[d];
  int ch = e / CHUNK_E;
  int pos = rowptr[d] + (int)base_tbl[(size_t)ch * N_NODES + d] + (int)r_local[e];
  int2 rec; rec.x = s; rec.y = __float_as_int(c);
  edges[pos] = rec;
}

// ---------- half-wave gather: 32 lanes cover a 128-wide fp16 row ----------
__device__ __forceinline__ float4 gather_row_half(
    const int* __restrict__ rowptr, const int2* __restrict__ edges,
    const uint2* __restrict__ xh /* row stride 32 */, int row, int sub) {
  int beg = rowptr[row], end = rowptr[row + 1];
  float4 acc = make_float4(0.f, 0.f, 0.f, 0.f);
  int e = beg;
  for (; e + 7 < end; e += 8) {
    int2 p0 = edges[e + 0], p1 = edges[e + 1], p2 = edges[e + 2], p3 = edges[e + 3];
    int2 p4 = edges[e + 4], p5 = edges[e + 5], p6 = edges[e + 6], p7 = edges[e + 7];
    uint2 q0 = xh[(size_t)p0.x * 32 + sub];
    uint2 q1 = xh[(size_t)p1.x * 32 + sub];
    uint2 q2 = xh[(size_t)p2.x * 32 + sub];
    uint2 q3 = xh[(size_t)p3.x * 32 + sub];
    uint2 q4 = xh[(size_t)p4.x * 32 + sub];
    uint2 q5 = xh[(size_t)p5.x * 32 + sub];
    uint2 q6 = xh[(size_t)p6.x * 32 + sub];
    uint2 q7 = xh[(size_t)p7.x * 32 + sub];
#define ACC_EDGE(P, Q)                                              \
    {                                                               \
      float cc = __int_as_float(P.y);                               \
      float2 lo = h2f2(Q.x);                                        \
      float2 hi = h2f2(Q.y);                                        \
      acc.x += cc * lo.x; acc.y += cc * lo.y;                       \
      acc.z += cc * hi.x; acc.w += cc * hi.y;                       \
    }
    ACC_EDGE(p0, q0) ACC_EDGE(p1, q1) ACC_EDGE(p2, q2) ACC_EDGE(p3, q3)
    ACC_EDGE(p4, q4) ACC_EDGE(p5, q5) ACC_EDGE(p6, q6) ACC_EDGE(p7, q7)
  }
  for (; e < end; ++e) {
    int2 p0 = edges[e];
    uint2 q0 = xh[(size_t)p0.x * 32 + sub];
    ACC_EDGE(p0, q0)
  }
#undef ACC_EDGE
  return acc;
}

// ---------- 5a. layer-1: spmm(fp16 g) + bias + selu + fused @W2 -> fp16 bufB ---
__global__ __launch_bounds__(256) void spmm_selu_gemm(
    const int* __restrict__ rowptr, const int2* __restrict__ edges,
    const uint2* __restrict__ g, const float* __restrict__ bias,
    const float* __restrict__ W, __half* __restrict__ out, int n) {
  __shared__ float hL[8 * 128];
  int wid = threadIdx.x >> 6, lane = threadIdx.x & 63;
  int half = lane >> 5, sub = lane & 31;
  int lrow = wid * 2 + half;                 // 0..7 within block
  int row = blockIdx.x * 8 + lrow;           // grid exact: row < n
  float4 a = gather_row_half(rowptr, edges, g, row, sub);
  float4 b = ((const float4*)bias)[sub];
  float4 h;
  h.x = selu_f(a.x + b.x);
  h.y = selu_f(a.y + b.y);
  h.z = selu_f(a.z + b.z);
  h.w = selu_f(a.w + b.w);
  ((float4*)hL)[lrow * 32 + sub] = h;
  __syncthreads();
  int col = threadIdx.x & 127;
  int rq = threadIdx.x >> 7;
  const float4* h4 = (const float4*)&hL[rq * 4 * 128];
  float acc0 = 0.f, acc1 = 0.f, acc2 = 0.f, acc3 = 0.f;
#pragma unroll 8
  for (int k4 = 0; k4 < 32; ++k4) {
    float w0 = W[(4 * k4 + 0) * 128 + col];
    float w1 = W[(4 * k4 + 1) * 128 + col];
    float w2 = W[(4 * k4 + 2) * 128 + col];
    float w3 = W[(4 * k4 + 3) * 128 + col];
    float4 h0 = h4[0 * 32 + k4];             // broadcast ds_read_b128
    float4 h1 = h4[1 * 32 + k4];
    float4 h2 = h4[2 * 32 + k4];
    float4 h3 = h4[3 * 32 + k4];
    acc0 += h0.x * w0 + h0.y * w1 + h0.z * w2 + h0.w * w3;
    acc1 += h1.x * w0 + h1.y * w1 + h1.z * w2 + h1.w * w3;
    acc2 += h2.x * w0 + h2.y * w1 + h2.z * w2 + h2.w * w3;
    acc3 += h3.x * w0 + h3.y * w1 + h3.z * w2 + h3.w * w3;
  }
  size_t r0 = (size_t)(blockIdx.x * 8 + rq * 4);
  out[(r0 + 0) * 128 + col] = __float2half_rn(acc0);
  out[(r0 + 1) * 128 + col] = __float2half_rn(acc1);
  out[(r0 + 2) * 128 + col] = __float2half_rn(acc2);
  out[(r0 + 3) * 128 + col] = __float2half_rn(acc3);
}

// ---------- 5b. layer-2: spmm(fp16 bufB) + bias + selu -> fp32 output ----------
__global__ __launch_bounds__(256) void spmm_ep(
    const int* __restrict__ rowptr, const int2* __restrict__ edges,
    const uint2* __restrict__ xh, const float* __restrict__ bias,
    float* __restrict__ out, int n) {
  int wid = threadIdx.x >> 6, lane = threadIdx.x & 63;
  int half = lane >> 5, sub = lane & 31;
  int row = blockIdx.x * 8 + wid * 2 + half;   // grid exact
  float4 a = gather_row_half(rowptr, edges, xh, row, sub);
  float4 b = ((const float4*)bias)[sub];
  float4 r;
  r.x = selu_f(a.x + b.x);
  r.y = selu_f(a.y + b.y);
  r.z = selu_f(a.z + b.z);
  r.w = selu_f(a.w + b.w);
  ((float4*)out)[(size_t)row * 32 + sub] = r;
}

extern "C" void kernel_launch(void* const* d_in, const int* in_sizes, int n_in,
                              void* d_out, int out_size, void* d_ws, size_t ws_size,
                              hipStream_t stream) {
  const float* x   = (const float*)d_in[0];
  const int*   src = (const int*)d_in[1];
  const int*   dst = (const int*)d_in[2];
  const float* ew  = (const float*)d_in[3];
  const float* W1  = (const float*)d_in[4];
  const float* b1  = (const float*)d_in[5];
  const float* W2  = (const float*)d_in[6];
  const float* b2  = (const float*)d_in[7];
  float* out = (float*)d_out;

  // workspace layout. src_part/dst_part (12.8 MB) alias bufB: parts are dead
  // after reduce_base; bufB first written in spmm_selu_gemm (later).
  char* ws = (char*)d_ws;
  u64*   src_part = (u64*)(ws + 0);             //  6,400,000 B  } alias
  u64*   dst_part = (u64*)(ws + 6400000);       //  6,400,000 B  } bufB
  __half* bufB    = (__half*)(ws + 0);          // 12,800,000 B  }
  __half* bufG    = (__half*)(ws + 12800000);   // 12,800,000 B
  int2*  edges    = (int2*)(ws + 25600000);     //  6,400,000 B (16B aligned)
  unsigned short* base_tbl = (unsigned short*)(ws + 32000000);  // 1,600,000 B
  unsigned short* r_local  = (unsigned short*)(ws + 33600000);  // 1,600,000 B
  float* inv_out  = (float*)(ws + 35200000);    //    200,000 B
  float* inv_in   = (float*)(ws + 35400000);    //    200,000 B
  int*   cnt_in   = (int*)(ws + 35600000);      //    200,000 B
  int*   rowptr   = (int*)(ws + 35800000);      //    200,004 B
  int*   partials = (int*)(ws + 36000004);      //        256 B

  const int NB1K = (N_NODES + 1023) / 1024;     // 49
  const int NB   = (N_NODES + 255) / 256;       // 196

  // 1. LDS-histogram degrees + rank capture || bufG = fp16(x @ W1). No atomics.
  fused_hist_gemm<<<HIST_BLOCKS + GEMM_BLOCKS, 256, 0, stream>>>(
      src, dst, ew, src_part, dst_part, r_local, x, W1, bufG);
  // 2. totals -> inv norms, cnt_in; per-chunk exclusive base table
  reduce_base<<<NB, 256, 0, stream>>>(src_part, dst_part, inv_out, inv_in,
                                      cnt_in, base_tbl);
  // 3. rowptr = exclusive scan of cnt_in
  scan_partial<<<NB1K, 256, 0, stream>>>(cnt_in, partials, N_NODES);
  scan_small<<<1, 64, 0, stream>>>(partials, NB1K);
  scan_write<<<NB1K, 256, 0, stream>>>(cnt_in, partials, rowptr, N_NODES);
  // 4. atomic-free CSR fill
  fill_kernel<<<EDGE_BLOCKS, 256, 0, stream>>>(src, dst, ew, inv_out, inv_in,
                                               rowptr, base_tbl, r_local, edges);

  const int RB8 = N_NODES / 8;                  // 6250 (8 rows / block, exact)

  // layer 1 + layer-2 GEMM: bufB = fp16( selu(A_hat·(x@W1) + b1) @ W2 )
  spmm_selu_gemm<<<RB8, 256, 0, stream>>>(rowptr, edges, (const uint2*)bufG,
                                          b1, W2, bufB, N_NODES);
  // layer 2: out = selu(A_hat·bufB + b2)
  spmm_ep<<<RB8, 256, 0, stream>>>(rowptr, edges, (const uint2*)bufB, b2,
                                   out, N_NODES);
}

// Round 8
// 327.513 us; speedup vs baseline: 1.0564x; 1.0564x over previous
//
#include <hip/hip_runtime.h>
#include <hip/hip_fp16.h>
#include <math.h>

#define N_NODES 50000
#define N_EDGES 800000
#define FEAT 128
#define EPS_W 1e-12f

// Q24 fixed-point packing: low 40 bits = sum of w*2^24, high 24 bits = count.
#define WSCALE 16777216.0f
#define MASK40 ((1ull << 40) - 1)

#define EDGE_BLOCKS 3125   // 800000 / 256
#define GEMM_BLOCKS 3125   // 50000 / 16
#define ROW_BLOCKS 3125    // 50000 / 16 (16 rows per spmm block)

typedef unsigned long long u64;

// ---------- helpers ----------
__device__ __forceinline__ float selu_f(float x) {
  const float scale = 1.0507009873554805f;
  const float alpha = 1.6732632423543772f;
  return x > 0.f ? scale * x : scale * alpha * expm1f(x);
}

__device__ __forceinline__ float2 h2f2(unsigned int u) {
  __half2 h = *reinterpret_cast<__half2*>(&u);
  return __half22float2(h);
}

// ---------- GEMM body: 16 rows of A (n x 128) @ W (128 x 128) -> fp16 out ------
__device__ __forceinline__ void gemm16_half_body(
    const float* __restrict__ A, const float* __restrict__ W,
    __half* __restrict__ out, int row0, int n, float* aL /*16*128 LDS*/) {
  for (int i = threadIdx.x; i < 16 * 128; i += 256) {
    int r = row0 + (i >> 7);
    aL[i] = (r < n) ? A[row0 * 128 + i] : 0.f;
  }
  __syncthreads();
  int col = threadIdx.x & 63;
  int rg = threadIdx.x >> 6;  // 0..3
  float acc[4][2] = {};
  const float4* a4 = (const float4*)&aL[rg * 4 * 128];
#pragma unroll 8
  for (int k4 = 0; k4 < 32; ++k4) {
    float w0 = W[(4 * k4 + 0) * 128 + col];
    float w1 = W[(4 * k4 + 1) * 128 + col];
    float w2 = W[(4 * k4 + 2) * 128 + col];
    float w3 = W[(4 * k4 + 3) * 128 + col];
    float e0 = W[(4 * k4 + 0) * 128 + col + 64];
    float e1 = W[(4 * k4 + 1) * 128 + col + 64];
    float e2 = W[(4 * k4 + 2) * 128 + col + 64];
    float e3 = W[(4 * k4 + 3) * 128 + col + 64];
#pragma unroll
    for (int r = 0; r < 4; ++r) {
      float4 a = a4[r * 32 + k4];
      acc[r][0] += a.x * w0 + a.y * w1 + a.z * w2 + a.w * w3;
      acc[r][1] += a.x * e0 + a.y * e1 + a.z * e2 + a.w * e3;
    }
  }
#pragma unroll
  for (int r = 0; r < 4; ++r) {
    int row = row0 + rg * 4 + r;
    if (row < n) {
      out[(size_t)row * 128 + col]      = __float2half_rn(acc[r][0]);
      out[(size_t)row * 128 + col + 64] = __float2half_rn(acc[r][1]);
    }
  }
}

// ---------- 1. FUSED: degree atomics + rank capture || x@W1 GEMM ----------
// Degree is fabric-atomic-rate bound (~22 atomics/ns, 2/edge structural floor);
// the GEMM's VALU work co-schedules under it (m114 co-residency). LDS-histogram
// alternative measured WORSE (r7: 8x edge re-read + occupancy collapse).
__global__ __launch_bounds__(256) void fused_deg_gemm(
    const int* __restrict__ src, const int* __restrict__ dst,
    const float* __restrict__ ew,
    u64* __restrict__ acc_out, u64* __restrict__ acc_in,
    unsigned short* __restrict__ rank,
    const float* __restrict__ x, const float* __restrict__ W1,
    __half* __restrict__ bufG) {
  __shared__ float aL[16 * 128];
  if (blockIdx.x & 1) {
    int e = (blockIdx.x >> 1) * 256 + threadIdx.x;
    if (e >= N_EDGES) return;
    int s = src[e], d = dst[e];
    float w = ew[e];
    u64 p = (1ull << 40) | (u64)llrintf(w * WSCALE);
    atomicAdd(&acc_out[s], p);
    u64 old = atomicAdd(&acc_in[d], p);
    rank[e] = (unsigned short)(old >> 40);   // in-edge rank of e within row d
  } else {
    int row0 = (blockIdx.x >> 1) * 16;
    gemm16_half_body(x, W1, bufG, row0, N_NODES, aL);
  }
}

// ---------- 2. per-node inverse norms + scan partials (fused) ----------
__global__ __launch_bounds__(256) void node_inv_scan(
    const u64* __restrict__ acc_out, const u64* __restrict__ acc_in,
    float* __restrict__ inv_out, float* __restrict__ inv_in,
    int* __restrict__ partials, int n) {
  __shared__ int sdata[256];
  int base = blockIdx.x * 1024;
  int sum = 0;
  for (int j = 0; j < 4; ++j) {
    int i = base + j * 256 + threadIdx.x;
    if (i < n) {
      u64 po = acc_out[i], pi = acc_in[i];
      float wo = (float)(po & MASK40) * (1.0f / WSCALE);
      float wi = (float)(pi & MASK40) * (1.0f / WSCALE);
      float co = (float)(po >> 40);
      float ci = (float)(pi >> 40);
      inv_out[i] = (1.0f / sqrtf(fmaxf(wo, EPS_W))) * (1.0f / sqrtf(fmaxf(co, 1.0f)));
      inv_in[i]  = (1.0f / sqrtf(fmaxf(wi, EPS_W))) * (1.0f / sqrtf(fmaxf(ci, 1.0f)));
      sum += (int)(pi >> 40);
    }
  }
  sdata[threadIdx.x] = sum;
  __syncthreads();
  for (int s = 128; s > 0; s >>= 1) {
    if (threadIdx.x < (unsigned)s) sdata[threadIdx.x] += sdata[threadIdx.x + s];
    __syncthreads();
  }
  if (threadIdx.x == 0) partials[blockIdx.x] = sdata[0];
}

__global__ void scan_small(int* __restrict__ partials, int nb) {
  int lane = threadIdx.x;  // launched with 64 threads, nb <= 64
  int v = (lane < nb) ? partials[lane] : 0;
  int incl = v;
#pragma unroll
  for (int off = 1; off < 64; off <<= 1) {
    int tv = __shfl_up(incl, off);
    if (lane >= off) incl += tv;
  }
  if (lane < nb) partials[lane] = incl - v;  // exclusive
}

__global__ __launch_bounds__(256) void scan_write(
    const u64* __restrict__ acc_in, const int* __restrict__ partials,
    int* __restrict__ rowptr, int n) {
  __shared__ int sh[256];
  int t = threadIdx.x;
  int base = blockIdx.x * 1024;
  int c[4], local[4], s = 0;
#pragma unroll
  for (int j = 0; j < 4; ++j) {
    int i = base + t * 4 + j;
    c[j] = (i < n) ? (int)(acc_in[i] >> 40) : 0;
    s += c[j];
    local[j] = s;  // inclusive within thread
  }
  sh[t] = s;
  __syncthreads();
  for (int off = 1; off < 256; off <<= 1) {
    int v = (t >= off) ? sh[t - off] : 0;
    __syncthreads();
    sh[t] += v;
    __syncthreads();
  }
  int thread_excl = sh[t] - s;
  int pbase = partials[blockIdx.x];
#pragma unroll
  for (int j = 0; j < 4; ++j) {
    int i = base + t * 4 + j;
    if (i < n) {
      int excl = pbase + thread_excl + local[j] - c[j];
      rowptr[i] = excl;
      if (i == n - 1) rowptr[n] = excl + c[j];
    }
  }
}

// ---------- 3. ATOMIC-FREE fill: pos = rowptr[dst] + rank ----------
__global__ __launch_bounds__(256) void fill_kernel(
    const int* __restrict__ src, const int* __restrict__ dst,
    const float* __restrict__ ew,
    const float* __restrict__ inv_out, const float* __restrict__ inv_in,
    const int* __restrict__ rowptr, const unsigned short* __restrict__ rank,
    int2* __restrict__ edges) {
  int e = blockIdx.x * 256 + threadIdx.x;
  if (e >= N_EDGES) return;
  int s = src[e], d = dst[e];
  float c = ew[e] * inv_out[s] * inv_in[d];
  int pos = rowptr[d] + (int)rank[e];
  int2 rec; rec.x = s; rec.y = __float_as_int(c);
  edges[pos] = rec;  // single 8B scattered store, no atomic
}

// ---------- quarter-wave gather: 16 lanes x uint4 cover a 128-wide fp16 row ----
// One wave processes 4 rows concurrently: per-edge VMEM instr count halves vs
// half-wave; unroll 8 x 4 quarters = 32 edges in flight per wave.
struct Acc8 { float4 lo, hi; };

__device__ __forceinline__ Acc8 gather_row_q(
    const int* __restrict__ rowptr, const int2* __restrict__ edges,
    const uint4* __restrict__ xq /* row stride 16 */, int row, int sub) {
  int beg = rowptr[row], end = rowptr[row + 1];
  Acc8 acc;
  acc.lo = make_float4(0.f, 0.f, 0.f, 0.f);
  acc.hi = make_float4(0.f, 0.f, 0.f, 0.f);
  int e = beg;
  for (; e + 7 < end; e += 8) {
    int2 p0 = edges[e + 0], p1 = edges[e + 1], p2 = edges[e + 2], p3 = edges[e + 3];
    int2 p4 = edges[e + 4], p5 = edges[e + 5], p6 = edges[e + 6], p7 = edges[e + 7];
    uint4 q0 = xq[(size_t)p0.x * 16 + sub];
    uint4 q1 = xq[(size_t)p1.x * 16 + sub];
    uint4 q2 = xq[(size_t)p2.x * 16 + sub];
    uint4 q3 = xq[(size_t)p3.x * 16 + sub];
    uint4 q4 = xq[(size_t)p4.x * 16 + sub];
    uint4 q5 = xq[(size_t)p5.x * 16 + sub];
    uint4 q6 = xq[(size_t)p6.x * 16 + sub];
    uint4 q7 = xq[(size_t)p7.x * 16 + sub];
#define ACC_EDGE(P, Q)                                              \
    {                                                               \
      float cc = __int_as_float(P.y);                               \
      float2 f0 = h2f2(Q.x), f1 = h2f2(Q.y);                        \
      float2 f2 = h2f2(Q.z), f3 = h2f2(Q.w);                        \
      acc.lo.x += cc * f0.x; acc.lo.y += cc * f0.y;                 \
      acc.lo.z += cc * f1.x; acc.lo.w += cc * f1.y;                 \
      acc.hi.x += cc * f2.x; acc.hi.y += cc * f2.y;                 \
      acc.hi.z += cc * f3.x; acc.hi.w += cc * f3.y;                 \
    }
    ACC_EDGE(p0, q0) ACC_EDGE(p1, q1) ACC_EDGE(p2, q2) ACC_EDGE(p3, q3)
    ACC_EDGE(p4, q4) ACC_EDGE(p5, q5) ACC_EDGE(p6, q6) ACC_EDGE(p7, q7)
  }
  for (; e < end; ++e) {
    int2 p0 = edges[e];
    uint4 q0 = xq[(size_t)p0.x * 16 + sub];
    ACC_EDGE(p0, q0)
  }
#undef ACC_EDGE
  return acc;
}

// ---------- 4a. layer-1: spmm(fp16 g) + bias + selu + fused @W2 -> fp16 bufB ---
// 16 rows/block: 4 waves x 4 quarter-wave rows. GEMM: 8 outputs/thread,
// 16-row W reuse (W2 L2 traffic halved vs 8-row blocks).
__global__ __launch_bounds__(256) void spmm_selu_gemm(
    const int* __restrict__ rowptr, const int2* __restrict__ edges,
    const uint4* __restrict__ g, const float* __restrict__ bias,
    const float* __restrict__ W, __half* __restrict__ out, int n) {
  __shared__ float hL[16 * 128];
  int wid = threadIdx.x >> 6, lane = threadIdx.x & 63;
  int q = lane >> 4, sub = lane & 15;
  int lrow = wid * 4 + q;                    // 0..15 within block
  int row = blockIdx.x * 16 + lrow;          // grid exact: row < n
  Acc8 a = gather_row_q(rowptr, edges, g, row, sub);
  const float4* b4 = (const float4*)bias;
  float4 blo = b4[sub * 2], bhi = b4[sub * 2 + 1];
  float4* hL4 = (float4*)hL;
  float4 h;
  h.x = selu_f(a.lo.x + blo.x);
  h.y = selu_f(a.lo.y + blo.y);
  h.z = selu_f(a.lo.z + blo.z);
  h.w = selu_f(a.lo.w + blo.w);
  hL4[lrow * 32 + sub * 2] = h;
  h.x = selu_f(a.hi.x + bhi.x);
  h.y = selu_f(a.hi.y + bhi.y);
  h.z = selu_f(a.hi.z + bhi.z);
  h.w = selu_f(a.hi.w + bhi.w);
  hL4[lrow * 32 + sub * 2 + 1] = h;
  __syncthreads();
  // GEMM: col = t&127; rq = t>>7 covers rows rq*8 .. rq*8+7
  int col = threadIdx.x & 127;
  int rq = threadIdx.x >> 7;
  const float4* h4 = (const float4*)&hL[rq * 8 * 128];
  float acc[8] = {};
#pragma unroll 4
  for (int k4 = 0; k4 < 32; ++k4) {
    float w0 = W[(4 * k4 + 0) * 128 + col];
    float w1 = W[(4 * k4 + 1) * 128 + col];
    float w2 = W[(4 * k4 + 2) * 128 + col];
    float w3 = W[(4 * k4 + 3) * 128 + col];
#pragma unroll
    for (int r = 0; r < 8; ++r) {
      float4 hr = h4[r * 32 + k4];           // wave-uniform ds_read_b128 (bcast)
      acc[r] += hr.x * w0 + hr.y * w1 + hr.z * w2 + hr.w * w3;
    }
  }
  size_t r0 = (size_t)(blockIdx.x * 16 + rq * 8);
#pragma unroll
  for (int r = 0; r < 8; ++r)
    out[(r0 + r) * 128 + col] = __float2half_rn(acc[r]);
}

// ---------- 4b. layer-2: spmm(fp16 bufB) + bias + selu -> fp32 output ----------
__global__ __launch_bounds__(256) void spmm_ep(
    const int* __restrict__ rowptr, const int2* __restrict__ edges,
    const uint4* __restrict__ xq, const float* __restrict__ bias,
    float* __restrict__ out, int n) {
  int wid = threadIdx.x >> 6, lane = threadIdx.x & 63;
  int q = lane >> 4, sub = lane & 15;
  int row = blockIdx.x * 16 + wid * 4 + q;   // grid exact
  Acc8 a = gather_row_q(rowptr, edges, xq, row, sub);
  const float4* b4 = (const float4*)bias;
  float4 blo = b4[sub * 2], bhi = b4[sub * 2 + 1];
  float4* o4 = (float4*)out;
  float4 r;
  r.x = selu_f(a.lo.x + blo.x);
  r.y = selu_f(a.lo.y + blo.y);
  r.z = selu_f(a.lo.z + blo.z);
  r.w = selu_f(a.lo.w + blo.w);
  o4[(size_t)row * 32 + sub * 2] = r;
  r.x = selu_f(a.hi.x + bhi.x);
  r.y = selu_f(a.hi.y + bhi.y);
  r.z = selu_f(a.hi.z + bhi.z);
  r.w = selu_f(a.hi.w + bhi.w);
  o4[(size_t)row * 32 + sub * 2 + 1] = r;
}

extern "C" void kernel_launch(void* const* d_in, const int* in_sizes, int n_in,
                              void* d_out, int out_size, void* d_ws, size_t ws_size,
                              hipStream_t stream) {
  const float* x   = (const float*)d_in[0];
  const int*   src = (const int*)d_in[1];
  const int*   dst = (const int*)d_in[2];
  const float* ew  = (const float*)d_in[3];
  const float* W1  = (const float*)d_in[4];
  const float* b1  = (const float*)d_in[5];
  const float* W2  = (const float*)d_in[6];
  const float* b2  = (const float*)d_in[7];
  float* out = (float*)d_out;

  // workspace layout (byte offsets; 8B for u64/int2, 16B for edges & fp16 bufs)
  char* ws = (char*)d_ws;
  u64*   acc_out  = (u64*)(ws + 0);             //   400,000 B
  u64*   acc_in   = (u64*)(ws + 400000);        //   400,000 B
  float* inv_out  = (float*)(ws + 800000);      //   200,000 B
  float* inv_in   = (float*)(ws + 1000000);     //   200,000 B
  int*   rowptr   = (int*)(ws + 1200000);       //   200,004 B
  int*   partials = (int*)(ws + 1400004);       //       256 B
  unsigned short* rank = (unsigned short*)(ws + 1400260);  // 1,600,000 B
  int2*  edges    = (int2*)(ws + 3000272);      // 6,400,000 B (16B aligned)
  __half* bufG    = (__half*)(ws + 9400272);    // 12,800,000 B (fp16)
  __half* bufB    = (__half*)(ws + 22200272);   // 12,800,000 B (fp16)

  // zero the two packed degree accumulators
  hipMemsetAsync(d_ws, 0, (size_t)(2 * N_NODES) * sizeof(u64), stream);

  const int NB1K = (N_NODES + 1023) / 1024;    // 49

  // 1. degree atomics + rank capture || bufG = fp16(x @ W1)  (overlapped)
  fused_deg_gemm<<<EDGE_BLOCKS + GEMM_BLOCKS, 256, 0, stream>>>(
      src, dst, ew, acc_out, acc_in, rank, x, W1, bufG);
  // 2. norms + CSR rowptr
  node_inv_scan<<<NB1K, 256, 0, stream>>>(acc_out, acc_in, inv_out, inv_in,
                                          partials, N_NODES);
  scan_small<<<1, 64, 0, stream>>>(partials, NB1K);
  scan_write<<<NB1K, 256, 0, stream>>>(acc_in, partials, rowptr, N_NODES);
  // 3. atomic-free CSR fill
  fill_kernel<<<EDGE_BLOCKS, 256, 0, stream>>>(src, dst, ew, inv_out, inv_in,
                                               rowptr, rank, edges);

  // layer 1 + layer-2 GEMM: bufB = fp16( selu(A_hat·(x@W1) + b1) @ W2 )
  spmm_selu_gemm<<<ROW_BLOCKS, 256, 0, stream>>>(rowptr, edges, (const uint4*)bufG,
                                                 b1, W2, bufB, N_NODES);
  // layer 2: out = selu(A_hat·bufB + b2)
  spmm_ep<<<ROW_BLOCKS, 256, 0, stream>>>(rowptr, edges, (const uint4*)bufB, b2,
                                          out, N_NODES);
}